// Round 3
// baseline (158.990 us; speedup 1.0000x reference)
//
#include <hip/hip_runtime.h>
#include <math.h>

#define A_ 5
#define C_ 20
#define N_ 64
#define H_ 52
#define W_ 52
#define HW_ (H_ * W_)        // 2704
#define M_ 32
#define CH_ (A_ * (5 + C_))  // 125
#define CPB 256              // cells per block (64 lanes x 4 cells)
#define NBLK_X ((HW_ + CPB - 1) / CPB)  // 11
#define NBLK (NBLK_X * N_)              // 704

// Block = 320 threads = 5 waves; wave a computes anchor a for 256 cells,
// 4 cells per lane so every x load is global_load_dwordx4 (1 KB/wave/inst).
// CE log-sum-exp computed FIRST so the 20xfloat4 score block dies before the
// IoU loop (register peak control); sc[label] re-fetched later (L2-hot).
__global__ __launch_bounds__(320, 3) void yolo_main(
    const float* __restrict__ x,       // (N, 125, H, W)
    const float* __restrict__ anchors, // (5, 2)
    const float* __restrict__ gt,      // (N, 32, 4)
    const int* __restrict__ glab,      // (N, 32)
    const void* img_h_p, const void* img_w_p,
    float* __restrict__ ws)            // SoA: (3, NBLK)
{
    // exchange: [component][anchor][cell] — stride-1 in cell
    __shared__ float s_c[5][A_][CPB];  // bi, bu, ov, ce, bb

    const int tid  = threadIdx.x;
    const int a    = tid >> 6;    // anchor 0..4 (wave id)
    const int lane = tid & 63;
    const int n    = blockIdx.y;
    const int cb   = blockIdx.x * CPB + lane * 4;   // first of 4 cells
    const bool valid = cb < HW_;   // HW_ % 4 == 0 -> all 4 valid together

    int ibw = *(const int*)img_w_p;
    float img_w = (ibw > 0 && ibw < 1000000) ? (float)ibw : *(const float*)img_w_p;
    int ibh = *(const int*)img_h_p;
    float img_h = (ibh > 0 && ibh < 1000000) ? (float)ibh : *(const float*)img_h_p;
    const float sx = img_w / (float)W_;   // 32
    const float sy = img_h / (float)H_;   // 32

    const float ax = anchors[2 * a];       // wave-uniform
    const float ay = anchors[2 * a + 1];

    float bi[4] = {0.f, 0.f, 0.f, 0.f};
    float bu[4] = {1.f, 1.f, 1.f, 1.f};
    int   bm[4] = {0, 0, 0, 0};
    float ov[4] = {0.f, 0.f, 0.f, 0.f};
    float ce[4] = {0.f, 0.f, 0.f, 0.f};
    float bb[4] = {0.f, 0.f, 0.f, 0.f};

    if (valid) {
        const size_t base = (size_t)n * CH_ * HW_ + (size_t)a * 25 * HW_ + cb;

        // ---- issue ALL x loads as dwordx4 ----
        float4 S[C_];
        #pragma unroll
        for (int j = 0; j < C_; ++j)
            S[j] = *(const float4*)(x + base + (size_t)(5 + j) * HW_);
        float4 T0 = *(const float4*)(x + base);
        float4 T1 = *(const float4*)(x + base + (size_t)HW_);
        float4 T2 = *(const float4*)(x + base + 2 * (size_t)HW_);
        float4 T3 = *(const float4*)(x + base + 3 * (size_t)HW_);
        float4 T4 = *(const float4*)(x + base + 4 * (size_t)HW_);

        // ---- CE partial: lse = mx + log(sum exp) per cell; frees S ----
        float lse[4];
        {
            const float* Sf = (const float*)S;  // S[j] components j*4+k
            #pragma unroll
            for (int k = 0; k < 4; ++k) {
                float mx = Sf[k];
                #pragma unroll
                for (int j = 1; j < C_; ++j) mx = fmaxf(mx, Sf[j * 4 + k]);
                float se = 0.f;
                #pragma unroll
                for (int j = 0; j < C_; ++j) se += __expf(Sf[j * 4 + k] - mx);
                lse[k] = mx + __logf(se);
            }
        }

        // ---- boxes per cell ----
        float x1[4], y1[4], x2[4], y2[4], ap[4];
        {
            const float* t0 = (const float*)&T0;
            const float* t1 = (const float*)&T1;
            const float* t2 = (const float*)&T2;
            const float* t3 = (const float*)&T3;
            const float* t4 = (const float*)&T4;
            #pragma unroll
            for (int k = 0; k < 4; ++k) {
                const int c  = cb + k;
                const int wi = c % W_;
                const int hi = c / W_;
                float bx = 1.f / (1.f + __expf(-t0[k])) + (float)wi * sx;
                float by = 1.f / (1.f + __expf(-t1[k])) + (float)hi * sy;
                float bw = sx * ax * __expf(t2[k]);
                float bh = sy * ay * __expf(t3[k]);
                x1[k] = bx; y1[k] = by; x2[k] = bx + bw; y2[k] = by + bh;
                ov[k] = 1.f / (1.f + __expf(-t4[k]));
                ap[k] = (x2[k] - x1[k]) * (y2[k] - y1[k]);  // match reference
            }
        }

        // ---- IoU argmax: m-outer (load g/area once), 4 cells inner ----
        const float4* gtv = (const float4*)(gt + (size_t)n * M_ * 4);
        #pragma unroll 4
        for (int m = 0; m < M_; ++m) {
            float4 g = gtv[m];                 // uniform -> scalar load
            float area = (g.z - g.x) * (g.w - g.y);
            #pragma unroll
            for (int k = 0; k < 4; ++k) {
                float wxi = fminf(x2[k], g.z) - fmaxf(x1[k], g.x);
                float hyi = fminf(y2[k], g.w) - fmaxf(y1[k], g.y);
                wxi = fmaxf(wxi, 0.f);
                hyi = fmaxf(hyi, 0.f);
                float inter = wxi * hyi;
                float uni = ap[k] + area - inter;
                if (inter * bu[k] > bi[k] * uni) { bi[k] = inter; bu[k] = uni; bm[k] = m; }
            }
        }

        // ---- per-cell bbox term + CE finish (divergent small gathers) ----
        #pragma unroll
        for (int k = 0; k < 4; ++k) {
            float4 g = ((const float4*)gt)[n * M_ + bm[k]];   // L1/L2-resident
            int lab = glab[n * M_ + bm[k]];
            float d0 = x1[k] - g.x;
            float d1 = y1[k] - g.y;
            float d2 = sqrtf(x2[k]) - sqrtf(g.z);
            float d3 = sqrtf(y2[k]) - sqrtf(g.w);
            bb[k] = d0 * d0 + d1 * d1 + d2 * d2 + d3 * d3;
            float sval = x[base + (size_t)(5 + lab) * HW_ + k];  // L2-hot reload
            ce[k] = lse[k] - sval;
        }
    }

    if (valid) {
        const int cl = lane * 4;
        #pragma unroll
        for (int k = 0; k < 4; ++k) {
            s_c[0][a][cl + k] = bi[k];
            s_c[1][a][cl + k] = bu[k];
            s_c[2][a][cl + k] = ov[k];
            s_c[3][a][cl + k] = ce[k];
            s_c[4][a][cl + k] = bb[k];
        }
    }
    __syncthreads();

    // ---- tail: threads 0..255 each select best anchor for one cell ----
    float obj = 0.f, bbx = 0.f, clf = 0.f;
    if (tid < 256 && (blockIdx.x * CPB + tid) < HW_) {
        const int t = tid;
        float Bi = 0.f, Bu = 1.f, O = 0.f, CE = 0.f, BB = 0.f;
        float bomax = -1e30f;
        #pragma unroll
        for (int aa = 0; aa < A_; ++aa) {
            float ci = s_c[0][aa][t];
            float cu = s_c[1][aa][t];
            float co = s_c[2][aa][t];
            bomax = fmaxf(bomax, co);
            bool upd = (aa == 0) || (ci * Bu > Bi * cu);
            if (upd) {
                Bi = ci; Bu = cu; O = co;
                CE = s_c[3][aa][t];
                BB = s_c[4][aa][t];
            }
        }
        if (Bi > 0.f) {
            float d = O - Bi / Bu;
            obj = d * d;
            bbx = BB;
            clf = CE;
        } else {
            obj = 0.5f * bomax * bomax;
        }
    }

    // block reduce: all 5 waves shuffle (wave 4 contributes zeros)
    #pragma unroll
    for (int off = 32; off > 0; off >>= 1) {
        obj += __shfl_down(obj, off, 64);
        bbx += __shfl_down(bbx, off, 64);
        clf += __shfl_down(clf, off, 64);
    }
    __shared__ float s_red[5][3];
    if ((tid & 63) == 0) {
        const int wid = tid >> 6;
        s_red[wid][0] = obj; s_red[wid][1] = bbx; s_red[wid][2] = clf;
    }
    __syncthreads();
    if (tid == 0) {
        float oo = 0.f, bs = 0.f, cc = 0.f;
        #pragma unroll
        for (int w = 0; w < 5; ++w) {
            oo += s_red[w][0]; bs += s_red[w][1]; cc += s_red[w][2];
        }
        const int bid = blockIdx.y * gridDim.x + blockIdx.x;
        ws[0 * NBLK + bid] = oo;
        ws[1 * NBLK + bid] = bs;
        ws[2 * NBLK + bid] = cc;
    }
}

__global__ __launch_bounds__(1024) void yolo_reduce(
    const float* __restrict__ ws, float* __restrict__ out)
{
    __shared__ float s_red[16][3];
    const int tid = threadIdx.x;
    float o = 0.f, b = 0.f, c = 0.f;
    for (int e = tid; e < NBLK; e += 1024) {   // 1 coalesced iteration
        o += ws[0 * NBLK + e];
        b += ws[1 * NBLK + e];
        c += ws[2 * NBLK + e];
    }
    #pragma unroll
    for (int off = 32; off > 0; off >>= 1) {
        o += __shfl_down(o, off, 64);
        b += __shfl_down(b, off, 64);
        c += __shfl_down(c, off, 64);
    }
    const int wid = tid >> 6;
    if ((tid & 63) == 0) {
        s_red[wid][0] = o; s_red[wid][1] = b; s_red[wid][2] = c;
    }
    __syncthreads();
    if (tid == 0) {
        float oo = 0.f, bb = 0.f, cc = 0.f;
        #pragma unroll
        for (int w = 0; w < 16; ++w) {
            oo += s_red[w][0]; bb += s_red[w][1]; cc += s_red[w][2];
        }
        out[0] = oo; out[1] = bb; out[2] = cc;
    }
}

extern "C" void kernel_launch(void* const* d_in, const int* in_sizes, int n_in,
                              void* d_out, int out_size, void* d_ws, size_t ws_size,
                              hipStream_t stream) {
    (void)in_sizes; (void)n_in; (void)out_size; (void)ws_size;
    const float* x    = (const float*)d_in[0];
    const float* anch = (const float*)d_in[1];
    const float* gt   = (const float*)d_in[2];
    const int*   gl   = (const int*)d_in[3];
    const void*  ih   = d_in[4];
    const void*  iw   = d_in[5];
    float* out = (float*)d_out;
    float* ws  = (float*)d_ws;

    dim3 grid(NBLK_X, N_);
    yolo_main<<<grid, dim3(320), 0, stream>>>(x, anch, gt, gl, ih, iw, ws);
    yolo_reduce<<<1, 1024, 0, stream>>>(ws, out);
}